// Round 6
// baseline (812.835 us; speedup 1.0000x reference)
//
#include <hip/hip_runtime.h>

#define HS 1024
#define VS 32000
#define BS 64
#define SS 2048
#define NCH 64
#define SCH (SS/NCH)   // 32 seq positions per wave-chunk

typedef __attribute__((ext_vector_type(4))) float f4v;
typedef __attribute__((ext_vector_type(8))) short s8v;

__device__ __forceinline__ float sigmf(float x) { return 1.0f / (1.0f + __expf(-x)); }

// fp32 -> bf16 (round-to-nearest-even), raw short bits
__device__ __forceinline__ short bf16c(float f) {
  unsigned u = __builtin_bit_cast(unsigned, f);
  u = (u + 0x7FFFu + ((u >> 16) & 1u)) >> 16;
  return (short)u;
}

// Monotonic ticket grid-barrier. Counter zeroed per-launch by a memset node.
// Safe: grid <= 2 blocks/CU * 256 CU (guaranteed by __launch_bounds__(256,2)),
// so all blocks are co-resident. Agent-scope atomics + threadfence for
// cross-XCD visibility of normal stores.
__device__ __forceinline__ void gridbar(unsigned* cnt, unsigned target) {
  __syncthreads();
  __threadfence();
  if (threadIdx.x == 0) {
    __hip_atomic_fetch_add(cnt, 1u, __ATOMIC_ACQ_REL, __HIP_MEMORY_SCOPE_AGENT);
    while (__hip_atomic_load(cnt, __ATOMIC_ACQUIRE, __HIP_MEMORY_SCOPE_AGENT) < target)
      __builtin_amdgcn_s_sleep(2);
  }
  __syncthreads();
  __threadfence();
}

// ---------------------------------------------------------------------------
// FRONT: prep -> GRU gates -> hnew -> qgemm   (384 blocks, 3 barriers)
// Frag layouts: N=64:  idx = ((kt*4  + ct)*64 + lane)*8 + j
//               N=1024: idx = ((kt*64 + nt)*64 + lane)*8 + j
//   element = src[kt*32 + (lane>>4)*8 + j][tile*16 + (lane&15)]
// attn_b dropped: per-b constant on every score -> cancels in softmax.
// ---------------------------------------------------------------------------
__global__ __launch_bounds__(256, 2) void k_front(
    const int* __restrict__ idx, const float* __restrict__ emb,
    const float* __restrict__ hid, const float* __restrict__ aw,
    const float* __restrict__ w_ih, const float* __restrict__ w_hh,
    const float* __restrict__ b_ih, const float* __restrict__ b_hh,
    float* __restrict__ ht, short* __restrict__ fx, short* __restrict__ fh,
    short* __restrict__ awf, float* __restrict__ gxt, float* __restrict__ ght,
    float* __restrict__ out_h, short* __restrict__ fcat,
    float* __restrict__ qrow, unsigned* __restrict__ bar) {
  __shared__ float red[4][4][4][64];   // 16 KB (gates phase)
  const int bid = blockIdx.x, tid = threadIdx.x;
  const int gid = bid * 256 + tid;

  // ---- phase A: prep (131072 work items over 98304 threads) ----
  for (int t = gid; t < 131072; t += 98304) {
    { // awf swizzle
      int lane = t & 63, nt = (t >> 6) & 63, kt = t >> 12;
      int kr = kt * 32 + ((lane >> 4) & 3) * 8;
      int col = nt * 16 + (lane & 15);
      const float* sp = aw + (size_t)kr * HS + col;
      s8v v;
#pragma unroll
      for (int j = 0; j < 8; j++) v[j] = bf16c(sp[(size_t)j * HS]);
      *(s8v*)(awf + (size_t)t * 8) = v;
    }
    if (t < 65536) { // ht gather
      int b = t >> 10, k = t & 1023;
      ht[k * BS + b] = hid[(size_t)b * HS + k];
    }
    if (t < 8192) { // fx from emb via idx
      int lane = t & 63, ct = (t >> 6) & 3, kt = t >> 8;
      int col = ct * 16 + (lane & 15);
      int kr = kt * 32 + ((lane >> 4) & 3) * 8;
      const float* sp = emb + (size_t)idx[col] * HS + kr;
      s8v v;
#pragma unroll
      for (int j = 0; j < 8; j++) v[j] = bf16c(sp[j]);
      *(s8v*)(fx + (size_t)t * 8) = v;
    } else if (t < 16384) { // fh from hid
      int t2 = t - 8192;
      int lane = t2 & 63, ct = (t2 >> 6) & 3, kt = t2 >> 8;
      int col = ct * 16 + (lane & 15);
      int kr = kt * 32 + ((lane >> 4) & 3) * 8;
      const float* sp = hid + (size_t)col * HS + kr;
      s8v v;
#pragma unroll
      for (int j = 0; j < 8; j++) v[j] = bf16c(sp[j]);
      *(s8v*)(fh + (size_t)t2 * 8) = v;
    }
  }
  gridbar(bar, 384);

  // ---- phase B: GRU gate GEMMs (384 vblocks = 192 m-tiles x 2) ----
  {
    int y = (bid >= 192) ? 1 : 0;
    int mt = bid - y * 192;
    const float* W    = y ? w_hh : w_ih;
    const short* xf   = y ? fh : fx;
    const float* bias = y ? b_hh : b_ih;
    float* dst        = y ? ght : gxt;
    int lane = tid & 63;
    int ks = tid >> 6;
    int row = mt * 16 + (lane & 15);
    const float* wp = W + (size_t)row * HS + ((lane >> 4) * 8);
    const s8v* xp = (const s8v*)xf + lane;
    f4v acc0 = {0,0,0,0}, acc1 = {0,0,0,0}, acc2 = {0,0,0,0}, acc3 = {0,0,0,0};
#pragma unroll 4
    for (int kk = 0; kk < 8; kk++) {
      int kt = ks * 8 + kk;
      float4 wa = *(const float4*)(wp + (size_t)kt * 32);
      float4 wb = *(const float4*)(wp + (size_t)kt * 32 + 4);
      s8v a;
      a[0] = bf16c(wa.x); a[1] = bf16c(wa.y); a[2] = bf16c(wa.z); a[3] = bf16c(wa.w);
      a[4] = bf16c(wb.x); a[5] = bf16c(wb.y); a[6] = bf16c(wb.z); a[7] = bf16c(wb.w);
      const s8v* xk = xp + (size_t)kt * 256;
      acc0 = __builtin_amdgcn_mfma_f32_16x16x32_bf16(a, xk[0],   acc0, 0, 0, 0);
      acc1 = __builtin_amdgcn_mfma_f32_16x16x32_bf16(a, xk[64],  acc1, 0, 0, 0);
      acc2 = __builtin_amdgcn_mfma_f32_16x16x32_bf16(a, xk[128], acc2, 0, 0, 0);
      acc3 = __builtin_amdgcn_mfma_f32_16x16x32_bf16(a, xk[192], acc3, 0, 0, 0);
    }
#pragma unroll
    for (int r = 0; r < 4; r++) {
      red[ks][0][r][lane] = acc0[r];
      red[ks][1][r][lane] = acc1[r];
      red[ks][2][r][lane] = acc2[r];
      red[ks][3][r][lane] = acc3[r];
    }
    __syncthreads();
    int ct = ks;
    int rr0 = mt * 16 + (lane >> 4) * 4;
    int col = ct * 16 + (lane & 15);
#pragma unroll
    for (int r = 0; r < 4; r++) {
      float v = red[0][ct][r][lane] + red[1][ct][r][lane] +
                red[2][ct][r][lane] + red[3][ct][r][lane] + bias[rr0 + r];
      dst[(size_t)(rr0 + r) * BS + col] = v;
    }
  }
  gridbar(bar, 768);

  // ---- phase C: GRU nonlinearity (65536 items, blocks 0..255) ----
  if (gid < 65536) {
    int b = gid & 63, i = gid >> 6;
    float r = sigmf(gxt[i * BS + b] + ght[i * BS + b]);
    float z = sigmf(gxt[(HS + i) * BS + b] + ght[(HS + i) * BS + b]);
    float n = tanhf(gxt[(2 * HS + i) * BS + b] + r * ght[(2 * HS + i) * BS + b]);
    float hn = (1.0f - z) * n + z * ht[i * BS + b];
    out_h[(size_t)b * HS + i] = hn;
    int kt = i >> 5, j = i & 7;
    int lane = (b & 15) | (((i >> 3) & 3) << 4);
    int ct = b >> 4;
    fcat[((size_t)((kt * 4 + ct) * 64 + lane)) * 8 + j] = bf16c(hn);
  }
  gridbar(bar, 1152);

  // ---- phase D: q = h_new @ aw (blocks 0..63) ----
  if (bid < 64) {
    int lane = tid & 63;
    int mt = tid >> 6;
    int nt = bid;
    const float* ap = out_h + (size_t)(mt * 16 + (lane & 15)) * HS + ((lane >> 4) * 8);
    const s8v* bp = (const s8v*)awf + (size_t)nt * 64 + lane;
    f4v acc = {0,0,0,0};
#pragma unroll 4
    for (int kt = 0; kt < 32; kt++) {
      float4 wa = *(const float4*)(ap + kt * 32);
      float4 wb = *(const float4*)(ap + kt * 32 + 4);
      s8v a;
      a[0] = bf16c(wa.x); a[1] = bf16c(wa.y); a[2] = bf16c(wa.z); a[3] = bf16c(wa.w);
      a[4] = bf16c(wb.x); a[5] = bf16c(wb.y); a[6] = bf16c(wb.z); a[7] = bf16c(wb.w);
      acc = __builtin_amdgcn_mfma_f32_16x16x32_bf16(a, bp[(size_t)kt * 4096], acc, 0, 0, 0);
    }
    int r0 = mt * 16 + (lane >> 4) * 4;
    int hcol = nt * 16 + (lane & 15);
#pragma unroll
    for (int r = 0; r < 4; r++)
      qrow[(size_t)(r0 + r) * HS + hcol] = acc[r];
  }
}

// ---------------------------------------------------------------------------
// ATTN: fused scores + online softmax + context. ONE WAVE per (b, chunk).
// ---------------------------------------------------------------------------
__global__ __launch_bounds__(256, 4) void k_attn(const float* __restrict__ enc,
    const float* __restrict__ qrow, float* __restrict__ scores,
    float* __restrict__ mch, float* __restrict__ lch, float* __restrict__ ctxp) {
  int lane = threadIdx.x & 63;
  int w = blockIdx.x * 4 + (threadIdx.x >> 6);   // 4096 waves
  int b = w & 63;
  int ch = w >> 6;                               // 0..63
  const float* qb = qrow + (size_t)b * HS + lane * 4;
  float4 q0 = *(const float4*)(qb + 0);
  float4 q1 = *(const float4*)(qb + 256);
  float4 q2 = *(const float4*)(qb + 512);
  float4 q3 = *(const float4*)(qb + 768);
  int s0 = ch * SCH;
  const float* ep = enc + ((size_t)s0 * BS + b) * HS + lane * 4;
  float4 e0 = *(const float4*)(ep + 0);
  float4 e1 = *(const float4*)(ep + 256);
  float4 e2 = *(const float4*)(ep + 512);
  float4 e3 = *(const float4*)(ep + 768);
  float m = -1e30f, l = 0.f;
  float4 a0 = {0,0,0,0}, a1 = {0,0,0,0}, a2 = {0,0,0,0}, a3 = {0,0,0,0};
  for (int si = 0; si < SCH; si++) {
    float4 c0 = e0, c1 = e1, c2 = e2, c3 = e3;
    if (si + 1 < SCH) {
      const float* np = ep + (size_t)BS * HS;
      e0 = *(const float4*)(np + 0);
      e1 = *(const float4*)(np + 256);
      e2 = *(const float4*)(np + 512);
      e3 = *(const float4*)(np + 768);
    }
    ep += (size_t)BS * HS;
    float d0 = fmaf(c0.x,q0.x, fmaf(c0.y,q0.y, fmaf(c0.z,q0.z, c0.w*q0.w)));
    float d1 = fmaf(c1.x,q1.x, fmaf(c1.y,q1.y, fmaf(c1.z,q1.z, c1.w*q1.w)));
    float d2 = fmaf(c2.x,q2.x, fmaf(c2.y,q2.y, fmaf(c2.z,q2.z, c2.w*q2.w)));
    float d3 = fmaf(c3.x,q3.x, fmaf(c3.y,q3.y, fmaf(c3.z,q3.z, c3.w*q3.w)));
    float p = (d0 + d1) + (d2 + d3);
#pragma unroll
    for (int off = 32; off; off >>= 1) p += __shfl_xor(p, off, 64);
    if (lane == 0) scores[(size_t)b * SS + s0 + si] = p;
    float mn = fmaxf(m, p);
    float sc = __expf(m - mn);     // first iter: exp(-huge) = 0
    float pr = __expf(p - mn);
    l = fmaf(l, sc, pr);
    a0.x = fmaf(a0.x, sc, pr * c0.x); a0.y = fmaf(a0.y, sc, pr * c0.y);
    a0.z = fmaf(a0.z, sc, pr * c0.z); a0.w = fmaf(a0.w, sc, pr * c0.w);
    a1.x = fmaf(a1.x, sc, pr * c1.x); a1.y = fmaf(a1.y, sc, pr * c1.y);
    a1.z = fmaf(a1.z, sc, pr * c1.z); a1.w = fmaf(a1.w, sc, pr * c1.w);
    a2.x = fmaf(a2.x, sc, pr * c2.x); a2.y = fmaf(a2.y, sc, pr * c2.y);
    a2.z = fmaf(a2.z, sc, pr * c2.z); a2.w = fmaf(a2.w, sc, pr * c2.w);
    a3.x = fmaf(a3.x, sc, pr * c3.x); a3.y = fmaf(a3.y, sc, pr * c3.y);
    a3.z = fmaf(a3.z, sc, pr * c3.z); a3.w = fmaf(a3.w, sc, pr * c3.w);
    m = mn;
  }
  if (lane == 0) { mch[b * NCH + ch] = m; lch[b * NCH + ch] = l; }
  float* cp = ctxp + ((size_t)(b * NCH + ch)) * HS + lane * 4;
  *(float4*)(cp + 0)   = a0;
  *(float4*)(cp + 256) = a1;
  *(float4*)(cp + 512) = a2;
  *(float4*)(cp + 768) = a3;
}

// ---------------------------------------------------------------------------
// BACK: combine -> concat GEMM -> output GEMM   (500 blocks, 2 barriers)
// ---------------------------------------------------------------------------
__global__ __launch_bounds__(256, 2) void k_back(
    const float* __restrict__ mch, const float* __restrict__ lch,
    const float* __restrict__ ctxp, const float* __restrict__ scores,
    short* __restrict__ fcat, float* __restrict__ wout,
    const float* __restrict__ cw, const float* __restrict__ cb,
    short* __restrict__ cbf, const float* __restrict__ ow,
    const float* __restrict__ ob, float* __restrict__ out0,
    unsigned* __restrict__ bar) {
  __shared__ float sm[NCH], sl[NCH], ssc[NCH];
  __shared__ float red[4][4][4][64];   // 16 KB (concat phase)
  const int bid = blockIdx.x, tid = threadIdx.x;

  // ---- phase A: combine chunk partials (vblocks 0..255 = 64 b x 4 hslice) --
  if (bid < 256) {
    int b = bid & 63, by = bid >> 6;
    int t = tid;
    if (t < NCH) { sm[t] = mch[b * NCH + t]; sl[t] = lch[b * NCH + t]; }
    __syncthreads();
    float mstar = -1e30f;
    for (int c = 0; c < NCH; c++) mstar = fmaxf(mstar, sm[c]);
    if (t < NCH) ssc[t] = __expf(sm[t] - mstar);
    __syncthreads();
    float L = 0.f;
    for (int c = 0; c < NCH; c++) L = fmaf(sl[c], ssc[c], L);
    float invL = 1.0f / L;
    int h = by * 256 + t;
    float acc = 0.f;
    for (int c = 0; c < NCH; c++)
      acc = fmaf(ctxp[((size_t)(b * NCH + c)) * HS + h], ssc[c], acc);
    float ctx = acc * invL;
    int kc = HS + h;
    int kt = kc >> 5, j = kc & 7;
    int lane2 = (b & 15) | (((kc >> 3) & 3) << 4);
    int ct = b >> 4;
    fcat[((size_t)((kt * 4 + ct) * 64 + lane2)) * 8 + j] = bf16c(ctx);
    if (by == 0)
      for (int s = t; s < SS; s += 256)
        wout[(size_t)b * SS + s] = __expf(scores[(size_t)b * SS + s] - mstar) * invL;
  }
  gridbar(bar, 500);

  // ---- phase B: concat GEMM (blocks 0..63), tanh -> bf16 cbf[b][k] ----
  if (bid < 64) {
    int lane = tid & 63;
    int ks = tid >> 6;
    int mt = bid;
    int row = mt * 16 + (lane & 15);
    const float* wp = cw + (size_t)row * (2 * HS) + ((lane >> 4) * 8);
    const s8v* xp = (const s8v*)fcat + lane;
    f4v acc0 = {0,0,0,0}, acc1 = {0,0,0,0}, acc2 = {0,0,0,0}, acc3 = {0,0,0,0};
#pragma unroll 4
    for (int kk = 0; kk < 16; kk++) {
      int kt = ks * 16 + kk;
      float4 wa = *(const float4*)(wp + (size_t)kt * 32);
      float4 wb = *(const float4*)(wp + (size_t)kt * 32 + 4);
      s8v a;
      a[0] = bf16c(wa.x); a[1] = bf16c(wa.y); a[2] = bf16c(wa.z); a[3] = bf16c(wa.w);
      a[4] = bf16c(wb.x); a[5] = bf16c(wb.y); a[6] = bf16c(wb.z); a[7] = bf16c(wb.w);
      const s8v* xk = xp + (size_t)kt * 256;
      acc0 = __builtin_amdgcn_mfma_f32_16x16x32_bf16(a, xk[0],   acc0, 0, 0, 0);
      acc1 = __builtin_amdgcn_mfma_f32_16x16x32_bf16(a, xk[64],  acc1, 0, 0, 0);
      acc2 = __builtin_amdgcn_mfma_f32_16x16x32_bf16(a, xk[128], acc2, 0, 0, 0);
      acc3 = __builtin_amdgcn_mfma_f32_16x16x32_bf16(a, xk[192], acc3, 0, 0, 0);
    }
#pragma unroll
    for (int r = 0; r < 4; r++) {
      red[ks][0][r][lane] = acc0[r];
      red[ks][1][r][lane] = acc1[r];
      red[ks][2][r][lane] = acc2[r];
      red[ks][3][r][lane] = acc3[r];
    }
    __syncthreads();
    int ct = ks;
    int rr0 = mt * 16 + (lane >> 4) * 4;
    int col = ct * 16 + (lane & 15);
#pragma unroll
    for (int r = 0; r < 4; r++) {
      float v = red[0][ct][r][lane] + red[1][ct][r][lane] +
                red[2][ct][r][lane] + red[3][ct][r][lane] + cb[rr0 + r];
      cbf[(size_t)col * HS + rr0 + r] = bf16c(tanhf(v));
    }
  }
  gridbar(bar, 1000);

  // ---- phase C: output GEMM (all 500 blocks) ----
  {
    int lane = tid & 63;
    int wv = tid >> 6;
    int nt = bid * 4 + wv;
    int v0 = nt * 16;
    const float* wp = ow + (size_t)(v0 + (lane & 15)) * HS + ((lane >> 4) * 8);
    const short* a0p = cbf + (size_t)(0  + (lane & 15)) * HS + ((lane >> 4) * 8);
    const short* a1p = a0p + (size_t)16 * HS;
    const short* a2p = a0p + (size_t)32 * HS;
    const short* a3p = a0p + (size_t)48 * HS;
    f4v acc0 = {0,0,0,0}, acc1 = {0,0,0,0}, acc2 = {0,0,0,0}, acc3 = {0,0,0,0};
#pragma unroll 4
    for (int kt = 0; kt < 32; kt++) {
      float4 wa = *(const float4*)(wp + kt * 32);
      float4 wb = *(const float4*)(wp + kt * 32 + 4);
      s8v bf;
      bf[0] = bf16c(wa.x); bf[1] = bf16c(wa.y); bf[2] = bf16c(wa.z); bf[3] = bf16c(wa.w);
      bf[4] = bf16c(wb.x); bf[5] = bf16c(wb.y); bf[6] = bf16c(wb.z); bf[7] = bf16c(wb.w);
      s8v fa0 = *(const s8v*)(a0p + kt * 32);
      s8v fa1 = *(const s8v*)(a1p + kt * 32);
      s8v fa2 = *(const s8v*)(a2p + kt * 32);
      s8v fa3 = *(const s8v*)(a3p + kt * 32);
      acc0 = __builtin_amdgcn_mfma_f32_16x16x32_bf16(fa0, bf, acc0, 0, 0, 0);
      acc1 = __builtin_amdgcn_mfma_f32_16x16x32_bf16(fa1, bf, acc1, 0, 0, 0);
      acc2 = __builtin_amdgcn_mfma_f32_16x16x32_bf16(fa2, bf, acc2, 0, 0, 0);
      acc3 = __builtin_amdgcn_mfma_f32_16x16x32_bf16(fa3, bf, acc3, 0, 0, 0);
    }
    float bv = ob[v0 + (lane & 15)];
    int rb = (lane >> 4) * 4;
    int vc = v0 + (lane & 15);
#pragma unroll
    for (int r = 0; r < 4; r++) {
      out0[(size_t)(0  + rb + r) * VS + vc] = acc0[r] + bv;
      out0[(size_t)(16 + rb + r) * VS + vc] = acc1[r] + bv;
      out0[(size_t)(32 + rb + r) * VS + vc] = acc2[r] + bv;
      out0[(size_t)(48 + rb + r) * VS + vc] = acc3[r] + bv;
    }
  }
}

// ---------------------------------------------------------------------------
extern "C" void kernel_launch(void* const* d_in, const int* in_sizes, int n_in,
                              void* d_out, int out_size, void* d_ws, size_t ws_size,
                              hipStream_t stream) {
  const int*   idx  = (const int*)d_in[0];
  const float* hid  = (const float*)d_in[1];
  const float* enc  = (const float*)d_in[2];
  const float* emb  = (const float*)d_in[3];
  const float* w_ih = (const float*)d_in[4];
  const float* w_hh = (const float*)d_in[5];
  const float* b_ih = (const float*)d_in[6];
  const float* b_hh = (const float*)d_in[7];
  const float* aw   = (const float*)d_in[8];
  // d_in[9] = attn_b: per-b constant on every score -> cancels in softmax.
  const float* cw   = (const float*)d_in[10];
  const float* cb   = (const float*)d_in[11];
  const float* ow   = (const float*)d_in[12];
  const float* ob   = (const float*)d_in[13];

  float* out0  = (float*)d_out;                   // [B, V]
  float* out_h = out0 + (size_t)BS * VS;          // [1, B, H]
  float* out_w = out_h + (size_t)BS * HS;         // [B, 1, S]

  // workspace (~22 MB)
  float* ws   = (float*)d_ws;
  float* gxt  = ws;                               // [3H][B]
  float* ght  = gxt + (size_t)3 * HS * BS;        // [3H][B]
  float* ht   = ght + (size_t)3 * HS * BS;        // [H][B]
  float* qrow = ht  + (size_t)HS * BS;            // [B][H]
  float* scr  = qrow + (size_t)HS * BS;           // [B][S]
  float* mch  = scr + (size_t)BS * SS;            // [B][NCH]
  float* lch  = mch + (size_t)BS * NCH;           // [B][NCH]
  float* ctxp = lch + (size_t)BS * NCH;           // [B*NCH][H]  (16 MB)
  short* awf  = (short*)(ctxp + (size_t)BS * NCH * HS);  // 1M shorts
  short* fx   = awf + (size_t)HS * HS;            // 64K shorts
  short* fh   = fx  + (size_t)HS * BS;            // 64K shorts
  short* fcat = fh  + (size_t)HS * BS;            // 128K shorts
  short* cbf  = fcat + (size_t)2 * HS * BS;       // 64K shorts
  unsigned* barf = (unsigned*)((((uintptr_t)(cbf + (size_t)HS * BS)) + 255)
                               & ~(uintptr_t)255);
  unsigned* barb = barf + 64;                     // separate cacheline

  hipMemsetAsync(barf, 0, 512, stream);           // zero both barrier counters
  k_front<<<dim3(384), dim3(256), 0, stream>>>(
      idx, emb, hid, aw, w_ih, w_hh, b_ih, b_hh,
      ht, fx, fh, awf, gxt, ght, out_h, fcat, qrow, barf);
  k_attn <<<dim3(BS * NCH / 4), dim3(256), 0, stream>>>(enc, qrow, scr, mch, lch, ctxp);
  k_back <<<dim3(VS / 64), dim3(256), 0, stream>>>(
      mch, lch, ctxp, scr, fcat, out_w, cw, cb, cbf, ow, ob, out0, barb);
}

// Round 7
// 685.637 us; speedup vs baseline: 1.1855x; 1.1855x over previous
//
#include <hip/hip_runtime.h>

#define HS 1024
#define VS 32000
#define BS 64
#define SS 2048
#define NCH 64
#define SCH (SS/NCH)   // 32 seq positions per wave-chunk

typedef __attribute__((ext_vector_type(4))) float f4v;
typedef __attribute__((ext_vector_type(8))) short s8v;

__device__ __forceinline__ float sigmf(float x) { return 1.0f / (1.0f + __expf(-x)); }

// fp32 -> bf16 (round-to-nearest-even), raw short bits
__device__ __forceinline__ short bf16c(float f) {
  unsigned u = __builtin_bit_cast(unsigned, f);
  u = (u + 0x7FFFu + ((u >> 16) & 1u)) >> 16;
  return (short)u;
}

// Monotonic ticket grid-barrier, zeroed per-launch by a memset node.
// Grid <= 2 blocks/CU * 256 CU (guaranteed by __launch_bounds__(256,2)).
// CRITICAL (round-6 post-mortem): poll with RELAXED loads — an ACQUIRE
// atomic load emits `buffer_inv sc1` (full XCD-L2 invalidate) PER POLL,
// which destroyed chip-wide memory performance (250 GB/s, VALU 1%).
// Acquire/release are paid ONCE via __threadfence() outside the spin:
//   release: fence (wbL2) before the count bump publishes prior stores;
//   acquire: fence (inv) after release drops stale L2 lines.
__device__ __forceinline__ void gridbar(unsigned* cnt, unsigned target) {
  __syncthreads();
  __threadfence();   // release side: publish prior stores to coherence point
  if (threadIdx.x == 0) {
    __hip_atomic_fetch_add(cnt, 1u, __ATOMIC_RELAXED, __HIP_MEMORY_SCOPE_AGENT);
    while (__hip_atomic_load(cnt, __ATOMIC_RELAXED, __HIP_MEMORY_SCOPE_AGENT) < target)
      __builtin_amdgcn_s_sleep(8);
  }
  __syncthreads();
  __threadfence();   // acquire side: invalidate stale cached lines (once)
}

// ---------------------------------------------------------------------------
// FRONT: prep -> GRU gates -> hnew -> qgemm   (384 blocks, 3 barriers)
// Frag layouts: N=64:  idx = ((kt*4  + ct)*64 + lane)*8 + j
//               N=1024: idx = ((kt*64 + nt)*64 + lane)*8 + j
//   element = src[kt*32 + (lane>>4)*8 + j][tile*16 + (lane&15)]
// attn_b dropped: per-b constant on every score -> cancels in softmax.
// ---------------------------------------------------------------------------
__global__ __launch_bounds__(256, 2) void k_front(
    const int* __restrict__ idx, const float* __restrict__ emb,
    const float* __restrict__ hid, const float* __restrict__ aw,
    const float* __restrict__ w_ih, const float* __restrict__ w_hh,
    const float* __restrict__ b_ih, const float* __restrict__ b_hh,
    float* __restrict__ ht, short* __restrict__ fx, short* __restrict__ fh,
    short* __restrict__ awf, float* __restrict__ gxt, float* __restrict__ ght,
    float* __restrict__ out_h, short* __restrict__ fcat,
    float* __restrict__ qrow, unsigned* __restrict__ bar) {
  __shared__ float red[4][4][4][64];   // 16 KB (gates phase)
  const int bid = blockIdx.x, tid = threadIdx.x;
  const int gid = bid * 256 + tid;

  // ---- phase A: prep (131072 work items over 98304 threads) ----
  for (int t = gid; t < 131072; t += 98304) {
    { // awf swizzle
      int lane = t & 63, nt = (t >> 6) & 63, kt = t >> 12;
      int kr = kt * 32 + ((lane >> 4) & 3) * 8;
      int col = nt * 16 + (lane & 15);
      const float* sp = aw + (size_t)kr * HS + col;
      s8v v;
#pragma unroll
      for (int j = 0; j < 8; j++) v[j] = bf16c(sp[(size_t)j * HS]);
      *(s8v*)(awf + (size_t)t * 8) = v;
    }
    if (t < 65536) { // ht gather
      int b = t >> 10, k = t & 1023;
      ht[k * BS + b] = hid[(size_t)b * HS + k];
    }
    if (t < 8192) { // fx from emb via idx
      int lane = t & 63, ct = (t >> 6) & 3, kt = t >> 8;
      int col = ct * 16 + (lane & 15);
      int kr = kt * 32 + ((lane >> 4) & 3) * 8;
      const float* sp = emb + (size_t)idx[col] * HS + kr;
      s8v v;
#pragma unroll
      for (int j = 0; j < 8; j++) v[j] = bf16c(sp[j]);
      *(s8v*)(fx + (size_t)t * 8) = v;
    } else if (t < 16384) { // fh from hid
      int t2 = t - 8192;
      int lane = t2 & 63, ct = (t2 >> 6) & 3, kt = t2 >> 8;
      int col = ct * 16 + (lane & 15);
      int kr = kt * 32 + ((lane >> 4) & 3) * 8;
      const float* sp = hid + (size_t)col * HS + kr;
      s8v v;
#pragma unroll
      for (int j = 0; j < 8; j++) v[j] = bf16c(sp[j]);
      *(s8v*)(fh + (size_t)t2 * 8) = v;
    }
  }
  gridbar(bar, 384);

  // ---- phase B: GRU gate GEMMs (384 vblocks = 192 m-tiles x 2) ----
  {
    int y = (bid >= 192) ? 1 : 0;
    int mt = bid - y * 192;
    const float* W    = y ? w_hh : w_ih;
    const short* xf   = y ? fh : fx;
    const float* bias = y ? b_hh : b_ih;
    float* dst        = y ? ght : gxt;
    int lane = tid & 63;
    int ks = tid >> 6;
    int row = mt * 16 + (lane & 15);
    const float* wp = W + (size_t)row * HS + ((lane >> 4) * 8);
    const s8v* xp = (const s8v*)xf + lane;
    f4v acc0 = {0,0,0,0}, acc1 = {0,0,0,0}, acc2 = {0,0,0,0}, acc3 = {0,0,0,0};
#pragma unroll 4
    for (int kk = 0; kk < 8; kk++) {
      int kt = ks * 8 + kk;
      float4 wa = *(const float4*)(wp + (size_t)kt * 32);
      float4 wb = *(const float4*)(wp + (size_t)kt * 32 + 4);
      s8v a;
      a[0] = bf16c(wa.x); a[1] = bf16c(wa.y); a[2] = bf16c(wa.z); a[3] = bf16c(wa.w);
      a[4] = bf16c(wb.x); a[5] = bf16c(wb.y); a[6] = bf16c(wb.z); a[7] = bf16c(wb.w);
      const s8v* xk = xp + (size_t)kt * 256;
      acc0 = __builtin_amdgcn_mfma_f32_16x16x32_bf16(a, xk[0],   acc0, 0, 0, 0);
      acc1 = __builtin_amdgcn_mfma_f32_16x16x32_bf16(a, xk[64],  acc1, 0, 0, 0);
      acc2 = __builtin_amdgcn_mfma_f32_16x16x32_bf16(a, xk[128], acc2, 0, 0, 0);
      acc3 = __builtin_amdgcn_mfma_f32_16x16x32_bf16(a, xk[192], acc3, 0, 0, 0);
    }
#pragma unroll
    for (int r = 0; r < 4; r++) {
      red[ks][0][r][lane] = acc0[r];
      red[ks][1][r][lane] = acc1[r];
      red[ks][2][r][lane] = acc2[r];
      red[ks][3][r][lane] = acc3[r];
    }
    __syncthreads();
    int ct = ks;
    int rr0 = mt * 16 + (lane >> 4) * 4;
    int col = ct * 16 + (lane & 15);
#pragma unroll
    for (int r = 0; r < 4; r++) {
      float v = red[0][ct][r][lane] + red[1][ct][r][lane] +
                red[2][ct][r][lane] + red[3][ct][r][lane] + bias[rr0 + r];
      dst[(size_t)(rr0 + r) * BS + col] = v;
    }
  }
  gridbar(bar, 768);

  // ---- phase C: GRU nonlinearity (65536 items, blocks 0..255) ----
  if (gid < 65536) {
    int b = gid & 63, i = gid >> 6;
    float r = sigmf(gxt[i * BS + b] + ght[i * BS + b]);
    float z = sigmf(gxt[(HS + i) * BS + b] + ght[(HS + i) * BS + b]);
    float n = tanhf(gxt[(2 * HS + i) * BS + b] + r * ght[(2 * HS + i) * BS + b]);
    float hn = (1.0f - z) * n + z * ht[i * BS + b];
    out_h[(size_t)b * HS + i] = hn;
    int kt = i >> 5, j = i & 7;
    int lane = (b & 15) | (((i >> 3) & 3) << 4);
    int ct = b >> 4;
    fcat[((size_t)((kt * 4 + ct) * 64 + lane)) * 8 + j] = bf16c(hn);
  }
  gridbar(bar, 1152);

  // ---- phase D: q = h_new @ aw (blocks 0..63) ----
  if (bid < 64) {
    int lane = tid & 63;
    int mt = tid >> 6;
    int nt = bid;
    const float* ap = out_h + (size_t)(mt * 16 + (lane & 15)) * HS + ((lane >> 4) * 8);
    const s8v* bp = (const s8v*)awf + (size_t)nt * 64 + lane;
    f4v acc = {0,0,0,0};
#pragma unroll 4
    for (int kt = 0; kt < 32; kt++) {
      float4 wa = *(const float4*)(ap + kt * 32);
      float4 wb = *(const float4*)(ap + kt * 32 + 4);
      s8v a;
      a[0] = bf16c(wa.x); a[1] = bf16c(wa.y); a[2] = bf16c(wa.z); a[3] = bf16c(wa.w);
      a[4] = bf16c(wb.x); a[5] = bf16c(wb.y); a[6] = bf16c(wb.z); a[7] = bf16c(wb.w);
      acc = __builtin_amdgcn_mfma_f32_16x16x32_bf16(a, bp[(size_t)kt * 4096], acc, 0, 0, 0);
    }
    int r0 = mt * 16 + (lane >> 4) * 4;
    int hcol = nt * 16 + (lane & 15);
#pragma unroll
    for (int r = 0; r < 4; r++)
      qrow[(size_t)(r0 + r) * HS + hcol] = acc[r];
  }
}

// ---------------------------------------------------------------------------
// ATTN: fused scores + online softmax + context. ONE WAVE per (b, chunk).
// ---------------------------------------------------------------------------
__global__ __launch_bounds__(256, 4) void k_attn(const float* __restrict__ enc,
    const float* __restrict__ qrow, float* __restrict__ scores,
    float* __restrict__ mch, float* __restrict__ lch, float* __restrict__ ctxp) {
  int lane = threadIdx.x & 63;
  int w = blockIdx.x * 4 + (threadIdx.x >> 6);   // 4096 waves
  int b = w & 63;
  int ch = w >> 6;                               // 0..63
  const float* qb = qrow + (size_t)b * HS + lane * 4;
  float4 q0 = *(const float4*)(qb + 0);
  float4 q1 = *(const float4*)(qb + 256);
  float4 q2 = *(const float4*)(qb + 512);
  float4 q3 = *(const float4*)(qb + 768);
  int s0 = ch * SCH;
  const float* ep = enc + ((size_t)s0 * BS + b) * HS + lane * 4;
  float4 e0 = *(const float4*)(ep + 0);
  float4 e1 = *(const float4*)(ep + 256);
  float4 e2 = *(const float4*)(ep + 512);
  float4 e3 = *(const float4*)(ep + 768);
  float m = -1e30f, l = 0.f;
  float4 a0 = {0,0,0,0}, a1 = {0,0,0,0}, a2 = {0,0,0,0}, a3 = {0,0,0,0};
  for (int si = 0; si < SCH; si++) {
    float4 c0 = e0, c1 = e1, c2 = e2, c3 = e3;
    if (si + 1 < SCH) {
      const float* np = ep + (size_t)BS * HS;
      e0 = *(const float4*)(np + 0);
      e1 = *(const float4*)(np + 256);
      e2 = *(const float4*)(np + 512);
      e3 = *(const float4*)(np + 768);
    }
    ep += (size_t)BS * HS;
    float d0 = fmaf(c0.x,q0.x, fmaf(c0.y,q0.y, fmaf(c0.z,q0.z, c0.w*q0.w)));
    float d1 = fmaf(c1.x,q1.x, fmaf(c1.y,q1.y, fmaf(c1.z,q1.z, c1.w*q1.w)));
    float d2 = fmaf(c2.x,q2.x, fmaf(c2.y,q2.y, fmaf(c2.z,q2.z, c2.w*q2.w)));
    float d3 = fmaf(c3.x,q3.x, fmaf(c3.y,q3.y, fmaf(c3.z,q3.z, c3.w*q3.w)));
    float p = (d0 + d1) + (d2 + d3);
#pragma unroll
    for (int off = 32; off; off >>= 1) p += __shfl_xor(p, off, 64);
    if (lane == 0) scores[(size_t)b * SS + s0 + si] = p;
    float mn = fmaxf(m, p);
    float sc = __expf(m - mn);     // first iter: exp(-huge) = 0
    float pr = __expf(p - mn);
    l = fmaf(l, sc, pr);
    a0.x = fmaf(a0.x, sc, pr * c0.x); a0.y = fmaf(a0.y, sc, pr * c0.y);
    a0.z = fmaf(a0.z, sc, pr * c0.z); a0.w = fmaf(a0.w, sc, pr * c0.w);
    a1.x = fmaf(a1.x, sc, pr * c1.x); a1.y = fmaf(a1.y, sc, pr * c1.y);
    a1.z = fmaf(a1.z, sc, pr * c1.z); a1.w = fmaf(a1.w, sc, pr * c1.w);
    a2.x = fmaf(a2.x, sc, pr * c2.x); a2.y = fmaf(a2.y, sc, pr * c2.y);
    a2.z = fmaf(a2.z, sc, pr * c2.z); a2.w = fmaf(a2.w, sc, pr * c2.w);
    a3.x = fmaf(a3.x, sc, pr * c3.x); a3.y = fmaf(a3.y, sc, pr * c3.y);
    a3.z = fmaf(a3.z, sc, pr * c3.z); a3.w = fmaf(a3.w, sc, pr * c3.w);
    m = mn;
  }
  if (lane == 0) { mch[b * NCH + ch] = m; lch[b * NCH + ch] = l; }
  float* cp = ctxp + ((size_t)(b * NCH + ch)) * HS + lane * 4;
  *(float4*)(cp + 0)   = a0;
  *(float4*)(cp + 256) = a1;
  *(float4*)(cp + 512) = a2;
  *(float4*)(cp + 768) = a3;
}

// ---------------------------------------------------------------------------
// BACK: combine -> concat GEMM -> output GEMM   (500 blocks, 2 barriers)
// ---------------------------------------------------------------------------
__global__ __launch_bounds__(256, 2) void k_back(
    const float* __restrict__ mch, const float* __restrict__ lch,
    const float* __restrict__ ctxp, const float* __restrict__ scores,
    short* __restrict__ fcat, float* __restrict__ wout,
    const float* __restrict__ cw, const float* __restrict__ cb,
    short* __restrict__ cbf, const float* __restrict__ ow,
    const float* __restrict__ ob, float* __restrict__ out0,
    unsigned* __restrict__ bar) {
  __shared__ float sm[NCH], sl[NCH], ssc[NCH];
  __shared__ float red[4][4][4][64];   // 16 KB (concat phase)
  const int bid = blockIdx.x, tid = threadIdx.x;

  // ---- phase A: combine chunk partials (vblocks 0..255 = 64 b x 4 hslice) --
  if (bid < 256) {
    int b = bid & 63, by = bid >> 6;
    int t = tid;
    if (t < NCH) { sm[t] = mch[b * NCH + t]; sl[t] = lch[b * NCH + t]; }
    __syncthreads();
    float mstar = -1e30f;
    for (int c = 0; c < NCH; c++) mstar = fmaxf(mstar, sm[c]);
    if (t < NCH) ssc[t] = __expf(sm[t] - mstar);
    __syncthreads();
    float L = 0.f;
    for (int c = 0; c < NCH; c++) L = fmaf(sl[c], ssc[c], L);
    float invL = 1.0f / L;
    int h = by * 256 + t;
    float acc = 0.f;
    for (int c = 0; c < NCH; c++)
      acc = fmaf(ctxp[((size_t)(b * NCH + c)) * HS + h], ssc[c], acc);
    float ctx = acc * invL;
    int kc = HS + h;
    int kt = kc >> 5, j = kc & 7;
    int lane2 = (b & 15) | (((kc >> 3) & 3) << 4);
    int ct = b >> 4;
    fcat[((size_t)((kt * 4 + ct) * 64 + lane2)) * 8 + j] = bf16c(ctx);
    if (by == 0)
      for (int s = t; s < SS; s += 256)
        wout[(size_t)b * SS + s] = __expf(scores[(size_t)b * SS + s] - mstar) * invL;
  }
  gridbar(bar, 500);

  // ---- phase B: concat GEMM (blocks 0..63), tanh -> bf16 cbf[b][k] ----
  if (bid < 64) {
    int lane = tid & 63;
    int ks = tid >> 6;
    int mt = bid;
    int row = mt * 16 + (lane & 15);
    const float* wp = cw + (size_t)row * (2 * HS) + ((lane >> 4) * 8);
    const s8v* xp = (const s8v*)fcat + lane;
    f4v acc0 = {0,0,0,0}, acc1 = {0,0,0,0}, acc2 = {0,0,0,0}, acc3 = {0,0,0,0};
#pragma unroll 4
    for (int kk = 0; kk < 16; kk++) {
      int kt = ks * 16 + kk;
      float4 wa = *(const float4*)(wp + (size_t)kt * 32);
      float4 wb = *(const float4*)(wp + (size_t)kt * 32 + 4);
      s8v a;
      a[0] = bf16c(wa.x); a[1] = bf16c(wa.y); a[2] = bf16c(wa.z); a[3] = bf16c(wa.w);
      a[4] = bf16c(wb.x); a[5] = bf16c(wb.y); a[6] = bf16c(wb.z); a[7] = bf16c(wb.w);
      const s8v* xk = xp + (size_t)kt * 256;
      acc0 = __builtin_amdgcn_mfma_f32_16x16x32_bf16(a, xk[0],   acc0, 0, 0, 0);
      acc1 = __builtin_amdgcn_mfma_f32_16x16x32_bf16(a, xk[64],  acc1, 0, 0, 0);
      acc2 = __builtin_amdgcn_mfma_f32_16x16x32_bf16(a, xk[128], acc2, 0, 0, 0);
      acc3 = __builtin_amdgcn_mfma_f32_16x16x32_bf16(a, xk[192], acc3, 0, 0, 0);
    }
#pragma unroll
    for (int r = 0; r < 4; r++) {
      red[ks][0][r][lane] = acc0[r];
      red[ks][1][r][lane] = acc1[r];
      red[ks][2][r][lane] = acc2[r];
      red[ks][3][r][lane] = acc3[r];
    }
    __syncthreads();
    int ct = ks;
    int rr0 = mt * 16 + (lane >> 4) * 4;
    int col = ct * 16 + (lane & 15);
#pragma unroll
    for (int r = 0; r < 4; r++) {
      float v = red[0][ct][r][lane] + red[1][ct][r][lane] +
                red[2][ct][r][lane] + red[3][ct][r][lane] + cb[rr0 + r];
      cbf[(size_t)col * HS + rr0 + r] = bf16c(tanhf(v));
    }
  }
  gridbar(bar, 1000);

  // ---- phase C: output GEMM (all 500 blocks) ----
  {
    int lane = tid & 63;
    int wv = tid >> 6;
    int nt = bid * 4 + wv;
    int v0 = nt * 16;
    const float* wp = ow + (size_t)(v0 + (lane & 15)) * HS + ((lane >> 4) * 8);
    const short* a0p = cbf + (size_t)(0  + (lane & 15)) * HS + ((lane >> 4) * 8);
    const short* a1p = a0p + (size_t)16 * HS;
    const short* a2p = a0p + (size_t)32 * HS;
    const short* a3p = a0p + (size_t)48 * HS;
    f4v acc0 = {0,0,0,0}, acc1 = {0,0,0,0}, acc2 = {0,0,0,0}, acc3 = {0,0,0,0};
#pragma unroll 4
    for (int kt = 0; kt < 32; kt++) {
      float4 wa = *(const float4*)(wp + kt * 32);
      float4 wb = *(const float4*)(wp + kt * 32 + 4);
      s8v bf;
      bf[0] = bf16c(wa.x); bf[1] = bf16c(wa.y); bf[2] = bf16c(wa.z); bf[3] = bf16c(wa.w);
      bf[4] = bf16c(wb.x); bf[5] = bf16c(wb.y); bf[6] = bf16c(wb.z); bf[7] = bf16c(wb.w);
      s8v fa0 = *(const s8v*)(a0p + kt * 32);
      s8v fa1 = *(const s8v*)(a1p + kt * 32);
      s8v fa2 = *(const s8v*)(a2p + kt * 32);
      s8v fa3 = *(const s8v*)(a3p + kt * 32);
      acc0 = __builtin_amdgcn_mfma_f32_16x16x32_bf16(fa0, bf, acc0, 0, 0, 0);
      acc1 = __builtin_amdgcn_mfma_f32_16x16x32_bf16(fa1, bf, acc1, 0, 0, 0);
      acc2 = __builtin_amdgcn_mfma_f32_16x16x32_bf16(fa2, bf, acc2, 0, 0, 0);
      acc3 = __builtin_amdgcn_mfma_f32_16x16x32_bf16(fa3, bf, acc3, 0, 0, 0);
    }
    float bv = ob[v0 + (lane & 15)];
    int rb = (lane >> 4) * 4;
    int vc = v0 + (lane & 15);
#pragma unroll
    for (int r = 0; r < 4; r++) {
      out0[(size_t)(0  + rb + r) * VS + vc] = acc0[r] + bv;
      out0[(size_t)(16 + rb + r) * VS + vc] = acc1[r] + bv;
      out0[(size_t)(32 + rb + r) * VS + vc] = acc2[r] + bv;
      out0[(size_t)(48 + rb + r) * VS + vc] = acc3[r] + bv;
    }
  }
}

// ---------------------------------------------------------------------------
extern "C" void kernel_launch(void* const* d_in, const int* in_sizes, int n_in,
                              void* d_out, int out_size, void* d_ws, size_t ws_size,
                              hipStream_t stream) {
  const int*   idx  = (const int*)d_in[0];
  const float* hid  = (const float*)d_in[1];
  const float* enc  = (const float*)d_in[2];
  const float* emb  = (const float*)d_in[3];
  const float* w_ih = (const float*)d_in[4];
  const float* w_hh = (const float*)d_in[5];
  const float* b_ih = (const float*)d_in[6];
  const float* b_hh = (const float*)d_in[7];
  const float* aw   = (const float*)d_in[8];
  // d_in[9] = attn_b: per-b constant on every score -> cancels in softmax.
  const float* cw   = (const float*)d_in[10];
  const float* cb   = (const float*)d_in[11];
  const float* ow   = (const float*)d_in[12];
  const float* ob   = (const float*)d_in[13];

  float* out0  = (float*)d_out;                   // [B, V]
  float* out_h = out0 + (size_t)BS * VS;          // [1, B, H]
  float* out_w = out_h + (size_t)BS * HS;         // [B, 1, S]

  // workspace (~22 MB)
  float* ws   = (float*)d_ws;
  float* gxt  = ws;                               // [3H][B]
  float* ght  = gxt + (size_t)3 * HS * BS;        // [3H][B]
  float* ht   = ght + (size_t)3 * HS * BS;        // [H][B]
  float* qrow = ht  + (size_t)HS * BS;            // [B][H]
  float* scr  = qrow + (size_t)HS * BS;           // [B][S]
  float* mch  = scr + (size_t)BS * SS;            // [B][NCH]
  float* lch  = mch + (size_t)BS * NCH;           // [B][NCH]
  float* ctxp = lch + (size_t)BS * NCH;           // [B*NCH][H]  (16 MB)
  short* awf  = (short*)(ctxp + (size_t)BS * NCH * HS);  // 1M shorts
  short* fx   = awf + (size_t)HS * HS;            // 64K shorts
  short* fh   = fx  + (size_t)HS * BS;            // 64K shorts
  short* fcat = fh  + (size_t)HS * BS;            // 128K shorts
  short* cbf  = fcat + (size_t)2 * HS * BS;       // 64K shorts
  unsigned* barf = (unsigned*)((((uintptr_t)(cbf + (size_t)HS * BS)) + 255)
                               & ~(uintptr_t)255);
  unsigned* barb = barf + 64;                     // separate cacheline

  hipMemsetAsync(barf, 0, 512, stream);           // zero both barrier counters
  k_front<<<dim3(384), dim3(256), 0, stream>>>(
      idx, emb, hid, aw, w_ih, w_hh, b_ih, b_hh,
      ht, fx, fh, awf, gxt, ght, out_h, fcat, qrow, barf);
  k_attn <<<dim3(BS * NCH / 4), dim3(256), 0, stream>>>(enc, qrow, scr, mch, lch, ctxp);
  k_back <<<dim3(VS / 64), dim3(256), 0, stream>>>(
      mch, lch, ctxp, scr, fcat, out_w, cw, cb, cbf, ow, ob, out0, barb);
}

// Round 8
// 210.120 us; speedup vs baseline: 3.8684x; 3.2631x over previous
//
#include <hip/hip_runtime.h>

#define HS 1024
#define VS 32000
#define BS 64
#define SS 2048
#define NCH 64
#define SCH (SS/NCH)   // 32 seq positions per wave-chunk

typedef __attribute__((ext_vector_type(4))) float f4v;
typedef __attribute__((ext_vector_type(8))) short s8v;

__device__ __forceinline__ float sigmf(float x) { return 1.0f / (1.0f + __expf(-x)); }

// fp32 -> bf16 (round-to-nearest-even), raw short bits
__device__ __forceinline__ short bf16c(float f) {
  unsigned u = __builtin_bit_cast(unsigned, f);
  u = (u + 0x7FFFu + ((u >> 16) & 1u)) >> 16;
  return (short)u;
}

// ---------------------------------------------------------------------------
// 1. prep: (a) swizzle aw [K=1024][N=1024] into MFMA B-frags (awf),
//    (b) build fx/fh B-frags (N=64) straight from emb/hid.
//    Frag layouts: N=64:  idx = ((kt*4  + ct)*64 + lane)*8 + j
//                  N=1024: idx = ((kt*64 + nt)*64 + lane)*8 + j
//    element = src[kt*32 + (lane>>4)*8 + j][tile*16 + (lane&15)]
// ---------------------------------------------------------------------------
__global__ __launch_bounds__(256) void k_prep(const int* __restrict__ idx,
    const float* __restrict__ emb, const float* __restrict__ hid,
    const float* __restrict__ aw,
    short* __restrict__ fx, short* __restrict__ fh, short* __restrict__ awf) {
  int t = blockIdx.x * 256 + threadIdx.x;   // 131072 threads
  { // awf
    int lane = t & 63, nt = (t >> 6) & 63, kt = t >> 12;   // kt 0..31
    int kr = kt * 32 + ((lane >> 4) & 3) * 8;
    int col = nt * 16 + (lane & 15);
    const float* sp = aw + (size_t)kr * HS + col;
    s8v v;
#pragma unroll
    for (int j = 0; j < 8; j++) v[j] = bf16c(sp[(size_t)j * HS]);
    *(s8v*)(awf + (size_t)t * 8) = v;
  }
  if (t < 8192) { // fx from emb via idx
    int lane = t & 63, ct = (t >> 6) & 3, kt = t >> 8;
    int col = ct * 16 + (lane & 15);
    int kr = kt * 32 + ((lane >> 4) & 3) * 8;
    const float* sp = emb + (size_t)idx[col] * HS + kr;
    s8v v;
#pragma unroll
    for (int j = 0; j < 8; j++) v[j] = bf16c(sp[j]);
    *(s8v*)(fx + (size_t)t * 8) = v;
  } else if (t < 16384) { // fh from hid
    int t2 = t - 8192;
    int lane = t2 & 63, ct = (t2 >> 6) & 3, kt = t2 >> 8;
    int col = ct * 16 + (lane & 15);
    int kr = kt * 32 + ((lane >> 4) & 3) * 8;
    const float* sp = hid + (size_t)col * HS + kr;
    s8v v;
#pragma unroll
    for (int j = 0; j < 8; j++) v[j] = bf16c(sp[j]);
    *(s8v*)(fh + (size_t)t2 * 8) = v;
  }
}

// ---------------------------------------------------------------------------
// 2. Split-K MFMA GEMM: dst[M][64] = W[M][K]@X. Block = one 16-row m-tile;
//    4 waves each own K/4; LDS combine. OL 0: fp32 dst[row*64+col] (gates).
//    OL 1: tanh -> bf16 dst[col*HS+row] (concat -> cbf).
// ---------------------------------------------------------------------------
template<int K, int OL>
__global__ __launch_bounds__(256) void mfsk(
    const float* __restrict__ W0, const short* __restrict__ xf0,
    const float* __restrict__ bias0, void* __restrict__ dst0,
    const float* __restrict__ W1, const short* __restrict__ xf1,
    const float* __restrict__ bias1, void* __restrict__ dst1) {
  const float* W    = blockIdx.y ? W1 : W0;
  const short* xf   = blockIdx.y ? xf1 : xf0;
  const float* bias = blockIdx.y ? bias1 : bias0;
  void* dst         = blockIdx.y ? dst1 : dst0;
  int lane = threadIdx.x & 63;
  int ks = threadIdx.x >> 6;           // k-slice 0..3
  int mt = blockIdx.x;                 // 16-row tile
  int row = mt * 16 + (lane & 15);
  const int KW = (K / 32) / 4;         // k-tiles per wave
  const float* wp = W + (size_t)row * K + ((lane >> 4) * 8);
  const s8v* xp = (const s8v*)xf + lane;
  f4v acc0 = {0,0,0,0}, acc1 = {0,0,0,0}, acc2 = {0,0,0,0}, acc3 = {0,0,0,0};
#pragma unroll 4
  for (int kk = 0; kk < KW; kk++) {
    int kt = ks * KW + kk;
    float4 wa = *(const float4*)(wp + (size_t)kt * 32);
    float4 wb = *(const float4*)(wp + (size_t)kt * 32 + 4);
    s8v a;
    a[0] = bf16c(wa.x); a[1] = bf16c(wa.y); a[2] = bf16c(wa.z); a[3] = bf16c(wa.w);
    a[4] = bf16c(wb.x); a[5] = bf16c(wb.y); a[6] = bf16c(wb.z); a[7] = bf16c(wb.w);
    const s8v* xk = xp + (size_t)kt * 256;
    acc0 = __builtin_amdgcn_mfma_f32_16x16x32_bf16(a, xk[0],   acc0, 0, 0, 0);
    acc1 = __builtin_amdgcn_mfma_f32_16x16x32_bf16(a, xk[64],  acc1, 0, 0, 0);
    acc2 = __builtin_amdgcn_mfma_f32_16x16x32_bf16(a, xk[128], acc2, 0, 0, 0);
    acc3 = __builtin_amdgcn_mfma_f32_16x16x32_bf16(a, xk[192], acc3, 0, 0, 0);
  }
  __shared__ float red[4][4][4][64];   // [ks][ct][r][lane] = 16 KB
#pragma unroll
  for (int r = 0; r < 4; r++) {
    red[ks][0][r][lane] = acc0[r];
    red[ks][1][r][lane] = acc1[r];
    red[ks][2][r][lane] = acc2[r];
    red[ks][3][r][lane] = acc3[r];
  }
  __syncthreads();
  int ct = ks;
  int rr0 = mt * 16 + (lane >> 4) * 4;
  int col = ct * 16 + (lane & 15);
#pragma unroll
  for (int r = 0; r < 4; r++) {
    float v = red[0][ct][r][lane] + red[1][ct][r][lane] +
              red[2][ct][r][lane] + red[3][ct][r][lane] + bias[rr0 + r];
    if (OL == 0)
      ((float*)dst)[(size_t)(rr0 + r) * BS + col] = v;
    else
      ((short*)dst)[(size_t)col * HS + rr0 + r] = bf16c(tanhf(v));
  }
}

// ---------------------------------------------------------------------------
// 3. GRU nonlinearity -> out_h [1,B,H] + fcat-low bf16 frags (k=i, col=b).
//    h is read straight from hid (L2/L3-resident; scattered 4B reads).
// ---------------------------------------------------------------------------
__global__ __launch_bounds__(256) void k_hnew(const float* __restrict__ gxt,
    const float* __restrict__ ght, const float* __restrict__ hid,
    float* __restrict__ out_h, short* __restrict__ fcat) {
  int tid = blockIdx.x * 256 + threadIdx.x;   // 65536
  int b = tid & 63, i = tid >> 6;
  float r = sigmf(gxt[i * BS + b] + ght[i * BS + b]);
  float z = sigmf(gxt[(HS + i) * BS + b] + ght[(HS + i) * BS + b]);
  float n = tanhf(gxt[(2 * HS + i) * BS + b] + r * ght[(2 * HS + i) * BS + b]);
  float hn = (1.0f - z) * n + z * hid[(size_t)b * HS + i];
  out_h[(size_t)b * HS + i] = hn;
  int kt = i >> 5, j = i & 7;
  int lane = (b & 15) | (((i >> 3) & 3) << 4);
  int ct = b >> 4;
  fcat[((size_t)((kt * 4 + ct) * 64 + lane)) * 8 + j] = bf16c(hn);
}

// ---------------------------------------------------------------------------
// 4. q = h_new @ aw via MFMA. A = out_h [b][g] (row-major, contiguous),
//    B = awf frags. attn_b dropped (per-b constant -> cancels in softmax).
// ---------------------------------------------------------------------------
__global__ __launch_bounds__(256) void k_qgemm(const float* __restrict__ hnr,
    const short* __restrict__ awf, float* __restrict__ qrow) {
  int lane = threadIdx.x & 63;
  int mt = threadIdx.x >> 6;    // b-tile 0..3
  int nt = blockIdx.x;          // h-tile 0..63
  const float* ap = hnr + (size_t)(mt * 16 + (lane & 15)) * HS + ((lane >> 4) * 8);
  const s8v* bp = (const s8v*)awf + (size_t)nt * 64 + lane;
  f4v acc = {0,0,0,0};
#pragma unroll 4
  for (int kt = 0; kt < 32; kt++) {
    float4 wa = *(const float4*)(ap + kt * 32);
    float4 wb = *(const float4*)(ap + kt * 32 + 4);
    s8v a;
    a[0] = bf16c(wa.x); a[1] = bf16c(wa.y); a[2] = bf16c(wa.z); a[3] = bf16c(wa.w);
    a[4] = bf16c(wb.x); a[5] = bf16c(wb.y); a[6] = bf16c(wb.z); a[7] = bf16c(wb.w);
    acc = __builtin_amdgcn_mfma_f32_16x16x32_bf16(a, bp[(size_t)kt * 4096], acc, 0, 0, 0);
  }
  int r0 = mt * 16 + (lane >> 4) * 4;
  int hcol = nt * 16 + (lane & 15);
#pragma unroll
  for (int r = 0; r < 4; r++)
    qrow[(size_t)(r0 + r) * HS + hcol] = acc[r];
}

// ---------------------------------------------------------------------------
// 5. Fused scores + online softmax + context: ONE WAVE per (b, chunk).
//    Lean register footprint: 1 position/iter + 1-ahead prefetch;
//    launch_bounds(256,4) guarantees >=16 waves/CU to hide HBM latency.
// ---------------------------------------------------------------------------
__global__ __launch_bounds__(256, 4) void k_attn(const float* __restrict__ enc,
    const float* __restrict__ qrow, float* __restrict__ scores,
    float* __restrict__ mch, float* __restrict__ lch, float* __restrict__ ctxp) {
  int lane = threadIdx.x & 63;
  int w = blockIdx.x * 4 + (threadIdx.x >> 6);   // 4096 waves
  int b = w & 63;
  int ch = w >> 6;                               // 0..63
  const float* qb = qrow + (size_t)b * HS + lane * 4;
  float4 q0 = *(const float4*)(qb + 0);
  float4 q1 = *(const float4*)(qb + 256);
  float4 q2 = *(const float4*)(qb + 512);
  float4 q3 = *(const float4*)(qb + 768);
  int s0 = ch * SCH;
  const float* ep = enc + ((size_t)s0 * BS + b) * HS + lane * 4;
  float4 e0 = *(const float4*)(ep + 0);
  float4 e1 = *(const float4*)(ep + 256);
  float4 e2 = *(const float4*)(ep + 512);
  float4 e3 = *(const float4*)(ep + 768);
  float m = -1e30f, l = 0.f;
  float4 a0 = {0,0,0,0}, a1 = {0,0,0,0}, a2 = {0,0,0,0}, a3 = {0,0,0,0};
  for (int si = 0; si < SCH; si++) {
    float4 c0 = e0, c1 = e1, c2 = e2, c3 = e3;
    if (si + 1 < SCH) {
      const float* np = ep + (size_t)BS * HS;
      e0 = *(const float4*)(np + 0);
      e1 = *(const float4*)(np + 256);
      e2 = *(const float4*)(np + 512);
      e3 = *(const float4*)(np + 768);
    }
    ep += (size_t)BS * HS;
    float d0 = fmaf(c0.x,q0.x, fmaf(c0.y,q0.y, fmaf(c0.z,q0.z, c0.w*q0.w)));
    float d1 = fmaf(c1.x,q1.x, fmaf(c1.y,q1.y, fmaf(c1.z,q1.z, c1.w*q1.w)));
    float d2 = fmaf(c2.x,q2.x, fmaf(c2.y,q2.y, fmaf(c2.z,q2.z, c2.w*q2.w)));
    float d3 = fmaf(c3.x,q3.x, fmaf(c3.y,q3.y, fmaf(c3.z,q3.z, c3.w*q3.w)));
    float p = (d0 + d1) + (d2 + d3);
#pragma unroll
    for (int off = 32; off; off >>= 1) p += __shfl_xor(p, off, 64);
    if (lane == 0) scores[(size_t)b * SS + s0 + si] = p;
    float mn = fmaxf(m, p);
    float sc = __expf(m - mn);     // first iter: exp(-huge) = 0
    float pr = __expf(p - mn);
    l = fmaf(l, sc, pr);
    a0.x = fmaf(a0.x, sc, pr * c0.x); a0.y = fmaf(a0.y, sc, pr * c0.y);
    a0.z = fmaf(a0.z, sc, pr * c0.z); a0.w = fmaf(a0.w, sc, pr * c0.w);
    a1.x = fmaf(a1.x, sc, pr * c1.x); a1.y = fmaf(a1.y, sc, pr * c1.y);
    a1.z = fmaf(a1.z, sc, pr * c1.z); a1.w = fmaf(a1.w, sc, pr * c1.w);
    a2.x = fmaf(a2.x, sc, pr * c2.x); a2.y = fmaf(a2.y, sc, pr * c2.y);
    a2.z = fmaf(a2.z, sc, pr * c2.z); a2.w = fmaf(a2.w, sc, pr * c2.w);
    a3.x = fmaf(a3.x, sc, pr * c3.x); a3.y = fmaf(a3.y, sc, pr * c3.y);
    a3.z = fmaf(a3.z, sc, pr * c3.z); a3.w = fmaf(a3.w, sc, pr * c3.w);
    m = mn;
  }
  if (lane == 0) { mch[b * NCH + ch] = m; lch[b * NCH + ch] = l; }
  float* cp = ctxp + ((size_t)(b * NCH + ch)) * HS + lane * 4;
  *(float4*)(cp + 0)   = a0;
  *(float4*)(cp + 256) = a1;
  *(float4*)(cp + 512) = a2;
  *(float4*)(cp + 768) = a3;
}

// ---------------------------------------------------------------------------
// 6. Combine chunk partials -> fcat-high bf16 frags + softmax weights output
// ---------------------------------------------------------------------------
__global__ __launch_bounds__(256) void k_combine(const float* __restrict__ mch,
    const float* __restrict__ lch, const float* __restrict__ ctxp,
    const float* __restrict__ scores, short* __restrict__ fcat,
    float* __restrict__ wout) {
  int b = blockIdx.x;
  int t = threadIdx.x;
  __shared__ float sm[NCH], sl[NCH], ssc[NCH];
  if (t < NCH) { sm[t] = mch[b * NCH + t]; sl[t] = lch[b * NCH + t]; }
  __syncthreads();
  float mstar = -1e30f;
  for (int c = 0; c < NCH; c++) mstar = fmaxf(mstar, sm[c]);
  if (t < NCH) ssc[t] = __expf(sm[t] - mstar);
  __syncthreads();
  float L = 0.f;
  for (int c = 0; c < NCH; c++) L = fmaf(sl[c], ssc[c], L);
  float invL = 1.0f / L;
  int h = blockIdx.y * 256 + t;
  float acc = 0.f;
  for (int c = 0; c < NCH; c++)
    acc = fmaf(ctxp[((size_t)(b * NCH + c)) * HS + h], ssc[c], acc);
  float ctx = acc * invL;
  int kc = HS + h;
  int kt = kc >> 5, j = kc & 7;
  int lane2 = (b & 15) | (((kc >> 3) & 3) << 4);
  int ct = b >> 4;
  fcat[((size_t)((kt * 4 + ct) * 64 + lane2)) * 8 + j] = bf16c(ctx);
  if (blockIdx.y == 0)
    for (int s = t; s < SS; s += 256)
      wout[(size_t)b * SS + s] = __expf(scores[(size_t)b * SS + s] - mstar) * invL;
}

// ---------------------------------------------------------------------------
// 7. output = concat_output @ out_w^T + out_b. A = cbf [b][k] bf16 (direct
//    16B frag loads), B = ow rows converted in-register. D[b][v] coalesced.
// ---------------------------------------------------------------------------
__global__ __launch_bounds__(256) void k_out2(const short* __restrict__ cbf,
    const float* __restrict__ ow, const float* __restrict__ ob,
    float* __restrict__ out0) {
  int lane = threadIdx.x & 63;
  int wv = threadIdx.x >> 6;
  int nt = blockIdx.x * 4 + wv;   // 0..1999 v-tiles
  int v0 = nt * 16;
  const float* wp = ow + (size_t)(v0 + (lane & 15)) * HS + ((lane >> 4) * 8);
  const short* a0p = cbf + (size_t)(0  + (lane & 15)) * HS + ((lane >> 4) * 8);
  const short* a1p = a0p + (size_t)16 * HS;
  const short* a2p = a0p + (size_t)32 * HS;
  const short* a3p = a0p + (size_t)48 * HS;
  f4v acc0 = {0,0,0,0}, acc1 = {0,0,0,0}, acc2 = {0,0,0,0}, acc3 = {0,0,0,0};
#pragma unroll 4
  for (int kt = 0; kt < 32; kt++) {
    float4 wa = *(const float4*)(wp + kt * 32);
    float4 wb = *(const float4*)(wp + kt * 32 + 4);
    s8v bf;
    bf[0] = bf16c(wa.x); bf[1] = bf16c(wa.y); bf[2] = bf16c(wa.z); bf[3] = bf16c(wa.w);
    bf[4] = bf16c(wb.x); bf[5] = bf16c(wb.y); bf[6] = bf16c(wb.z); bf[7] = bf16c(wb.w);
    s8v fa0 = *(const s8v*)(a0p + kt * 32);
    s8v fa1 = *(const s8v*)(a1p + kt * 32);
    s8v fa2 = *(const s8v*)(a2p + kt * 32);
    s8v fa3 = *(const s8v*)(a3p + kt * 32);
    acc0 = __builtin_amdgcn_mfma_f32_16x16x32_bf16(fa0, bf, acc0, 0, 0, 0);
    acc1 = __builtin_amdgcn_mfma_f32_16x16x32_bf16(fa1, bf, acc1, 0, 0, 0);
    acc2 = __builtin_amdgcn_mfma_f32_16x16x32_bf16(fa2, bf, acc2, 0, 0, 0);
    acc3 = __builtin_amdgcn_mfma_f32_16x16x32_bf16(fa3, bf, acc3, 0, 0, 0);
  }
  float bv = ob[v0 + (lane & 15)];
  int rb = (lane >> 4) * 4;
  int vc = v0 + (lane & 15);
#pragma unroll
  for (int r = 0; r < 4; r++) {
    out0[(size_t)(0  + rb + r) * VS + vc] = acc0[r] + bv;
    out0[(size_t)(16 + rb + r) * VS + vc] = acc1[r] + bv;
    out0[(size_t)(32 + rb + r) * VS + vc] = acc2[r] + bv;
    out0[(size_t)(48 + rb + r) * VS + vc] = acc3[r] + bv;
  }
}

// ---------------------------------------------------------------------------
extern "C" void kernel_launch(void* const* d_in, const int* in_sizes, int n_in,
                              void* d_out, int out_size, void* d_ws, size_t ws_size,
                              hipStream_t stream) {
  const int*   idx  = (const int*)d_in[0];
  const float* hid  = (const float*)d_in[1];
  const float* enc  = (const float*)d_in[2];
  const float* emb  = (const float*)d_in[3];
  const float* w_ih = (const float*)d_in[4];
  const float* w_hh = (const float*)d_in[5];
  const float* b_ih = (const float*)d_in[6];
  const float* b_hh = (const float*)d_in[7];
  const float* aw   = (const float*)d_in[8];
  // d_in[9] = attn_b: per-b constant on every score -> cancels in softmax.
  const float* cw   = (const float*)d_in[10];
  const float* cb   = (const float*)d_in[11];
  const float* ow   = (const float*)d_in[12];
  const float* ob   = (const float*)d_in[13];

  float* out0  = (float*)d_out;                   // [B, V]
  float* out_h = out0 + (size_t)BS * VS;          // [1, B, H]
  float* out_w = out_h + (size_t)BS * HS;         // [B, 1, S]

  // workspace (~22 MB)
  float* ws   = (float*)d_ws;
  float* gxt  = ws;                               // [3H][B]
  float* ght  = gxt + (size_t)3 * HS * BS;        // [3H][B]
  float* qrow = ght + (size_t)3 * HS * BS;        // [B][H]
  float* scr  = qrow + (size_t)HS * BS;           // [B][S]
  float* mch  = scr + (size_t)BS * SS;            // [B][NCH]
  float* lch  = mch + (size_t)BS * NCH;           // [B][NCH]
  float* ctxp = lch + (size_t)BS * NCH;           // [B*NCH][H]  (16 MB)
  short* awf  = (short*)(ctxp + (size_t)BS * NCH * HS);  // 1M shorts
  short* fx   = awf + (size_t)HS * HS;            // 64K shorts
  short* fh   = fx  + (size_t)HS * BS;            // 64K shorts
  short* fcat = fh  + (size_t)HS * BS;            // 128K shorts
  short* cbf  = fcat + (size_t)2 * HS * BS;       // 64K shorts

  k_prep   <<<dim3(512), dim3(256), 0, stream>>>(idx, emb, hid, aw, fx, fh, awf);
  mfsk<HS, 0><<<dim3(3 * HS / 16, 2), dim3(256), 0, stream>>>(
      w_ih, fx, b_ih, gxt, w_hh, fh, b_hh, ght);
  k_hnew   <<<dim3(HS * BS / 256), dim3(256), 0, stream>>>(gxt, ght, hid, out_h, fcat);
  k_qgemm  <<<dim3(HS / 16), dim3(256), 0, stream>>>(out_h, awf, qrow);
  k_attn   <<<dim3(BS * NCH / 4), dim3(256), 0, stream>>>(enc, qrow, scr, mch, lch, ctxp);
  k_combine<<<dim3(BS, 4), dim3(256), 0, stream>>>(mch, lch, ctxp, scr, fcat, out_w);
  mfsk<2 * HS, 1><<<dim3(HS / 16, 1), dim3(256), 0, stream>>>(
      cw, fcat, cb, cbf, cw, fcat, cb, cbf);
  k_out2   <<<dim3(VS / 64), dim3(256), 0, stream>>>(cbf, ow, ob, out0);
}